// Round 4
// baseline (466.260 us; speedup 1.0000x reference)
//
#include <hip/hip_runtime.h>
#include <hip/hip_bf16.h>
#include <stdint.h>

typedef unsigned int u32;
typedef unsigned short u16;
typedef float v2f __attribute__((ext_vector_type(2)));
typedef short bf16x8 __attribute__((ext_vector_type(8)));
typedef float f32x4 __attribute__((ext_vector_type(4)));

#define LN_EPS_ 1e-5f
#define EPS_ 1e-8f

__device__ __forceinline__ float bflo(u32 v){ return __uint_as_float(v << 16); }
__device__ __forceinline__ float bfhi(u32 v){ return __uint_as_float(v & 0xFFFF0000u); }
__device__ __forceinline__ u32 f2bf(float f){
    u32 x = __float_as_uint(f);
    return (x + 0x7FFFu + ((x >> 16) & 1u)) >> 16;
}
__device__ __forceinline__ u32 pack2bf(float a, float b){
    union { __hip_bfloat162 h; u32 u; } cv;
    cv.h = __float22bfloat162_rn(float2{a, b});
    return cv.u;
}
// packed fp32 math (gfx90a+/gfx950): 2 MACs per instruction
__device__ __forceinline__ v2f pkfma(v2f a, v2f b, v2f c){
    v2f d; asm("v_pk_fma_f32 %0, %1, %2, %3" : "=v"(d) : "v"(a), "v"(b), "v"(c)); return d;
}
__device__ __forceinline__ v2f pkadd(v2f a, v2f b){
    v2f d; asm("v_pk_add_f32 %0, %1, %2" : "=v"(d) : "v"(a), "v"(b)); return d;
}
__device__ __forceinline__ bf16x8 as_bf16x8(uint4 u){
    union { uint4 a; bf16x8 b; } c; c.a = u; return c.b;
}

// ---------------- kernel P: one-time weight prep ---------------------------
__global__ __launch_bounds__(256) void k_pack(
    const float* __restrict__ Wq, const float* __restrict__ Wv,
    const float* __restrict__ Wih, const float* __restrict__ Whh,
    const float* __restrict__ w1, const float* __restrict__ w2,
    float* __restrict__ WqT, u32* __restrict__ Pv, u32* __restrict__ Pih,
    u32* __restrict__ Phh, u32* __restrict__ Pw1, u32* __restrict__ Pw2,
    u32* __restrict__ Rg32)
{
    int i = blockIdx.x * 256 + threadIdx.x;
    if (i < 8192) {                                   // Pv
        int dp = i >> 7, o = i & 127;
        Pv[i] = pack2bf(Wv[o * 128 + 2 * dp], Wv[o * 128 + 2 * dp + 1]);
    } else if (i < 32768) {                           // Pih
        int r = i - 8192; int dp = r / 384, j = r - dp * 384;
        Pih[r] = pack2bf(Wih[j * 128 + 2 * dp], Wih[j * 128 + 2 * dp + 1]);
    } else if (i < 57344) {                           // Phh
        int r = i - 32768; int dp = r / 384, j = r - dp * 384;
        Phh[r] = pack2bf(Whh[j * 128 + 2 * dp], Whh[j * 128 + 2 * dp + 1]);
    } else if (i < 73728) {                           // Pw1
        int r = i - 57344; int dp = r >> 8, j = r & 255;
        Pw1[r] = pack2bf(w1[j * 128 + 2 * dp], w1[j * 128 + 2 * dp + 1]);
    } else if (i < 90112) {                           // Pw2
        int r = i - 73728; int mp = r >> 7, o = r & 127;
        Pw2[r] = pack2bf(w2[o * 256 + 2 * mp], w2[o * 256 + 2 * mp + 1]);
    } else if (i < 106496) {                          // WqT fp32
        int r = i - 90112; int d = r >> 7, o = r & 127;
        WqT[r] = Wq[o * 128 + d];
    } else if (i < 143360) {                          // zero Rg rows 7..15
        int r = i - 106496; int b = r / 576, rem = r - b * 576;
        Rg32[b * 1024 + 448 + rem] = 0;
    }
}

// ---------------- prep tail: LN(slot) -> q -> r -> Rg/c1/c2, zero accums ---
// 256 threads; lo half (t<128) holds nv = new slot value for h = t&127.
__device__ __forceinline__ void prep_tail(
    int b, int s, int h, int half, int t, float nv,
    const float* __restrict__ g_s, const float* __restrict__ b_s,
    const float* __restrict__ WqT, const float* __restrict__ Wk,
    const float* __restrict__ g_in, const float* __restrict__ b_in,
    u16* __restrict__ Rg, float* __restrict__ c1ws, float* __restrict__ c2ws,
    float* __restrict__ yws, float* __restrict__ Zws, float* __restrict__ Aws,
    float* snb, float* qb, float* xch, float* red4)
{
    if (!half) {
        float smv = nv, sqv = nv * nv;
        for (int m = 32; m >= 1; m >>= 1) { smv += __shfl_xor(smv, m); sqv += __shfl_xor(sqv, m); }
        if ((t & 63) == 0) { red4[(t >> 6) * 2] = smv; red4[(t >> 6) * 2 + 1] = sqv; }
    }
    __syncthreads();
    float mean = (red4[0] + red4[2]) * (1.0f / 128.0f);
    float var  = (red4[1] + red4[3]) * (1.0f / 128.0f) - mean * mean;
    float rsv = rsqrtf(var + LN_EPS_);
    if (!half) snb[h] = (nv - mean) * rsv * g_s[h] + b_s[h];
    __syncthreads();
    // q[h] = sum_d WqT[d][h] * snb[d], split-K over halves
    {
        float q0 = 0.f, q1 = 0.f;
        int d0 = half * 64;
        #pragma unroll 4
        for (int d = d0; d < d0 + 64; d += 2) {
            q0 += WqT[d * 128 + h] * snb[d];
            q1 += WqT[(d + 1) * 128 + h] * snb[d + 1];
        }
        if (half) xch[h] = q0 + q1;
        __syncthreads();
        if (!half) qb[h] = q0 + q1 + xch[h];
        __syncthreads();
    }
    // r[h] = sum_j Wk[j][h] * qb[j], split-K over halves
    float r0 = 0.f, r1 = 0.f;
    int j0 = half * 64;
    #pragma unroll 4
    for (int j = j0; j < j0 + 64; j += 2) {
        r0 += Wk[j * 128 + h] * qb[j];
        r1 += Wk[(j + 1) * 128 + h] * qb[j + 1];
    }
    if (half) xch[h] = r0 + r1;
    __syncthreads();
    if (!half) {
        float r = (r0 + r1 + xch[h]) * 0.08838834764831845f;   // 128^-0.5
        float rt  = g_in[h] * r;
        float c2v = b_in[h] * r;
        Rg[((size_t)b * 16 + s) * 128 + h] = (u16)f2bf(rt);
        float c1p = rt, c2p = c2v;
        for (int m = 32; m >= 1; m >>= 1) { c1p += __shfl_xor(c1p, m); c2p += __shfl_xor(c2p, m); }
        if ((t & 63) == 0) { red4[(t >> 6) * 2] = c1p; red4[(t >> 6) * 2 + 1] = c2p; }
        yws[(b * 7 + s) * 128 + h] = 0.f;
    }
    __syncthreads();
    if (t == 0) {
        c1ws[b * 8 + s] = red4[0] + red4[2];
        c2ws[b * 8 + s] = red4[1] + red4[3];
        Zws[b * 8 + s] = 0.f;
        Aws[b * 8 + s] = 0.f;
    }
}

// ---------------- kernel 0: slots init + prep for iter 0 -------------------
__global__ __launch_bounds__(256) void k_init_prep(
    const float* __restrict__ slots_init, const float* __restrict__ mu,
    const float* __restrict__ ls, float* __restrict__ slots,
    const float* __restrict__ g_s, const float* __restrict__ b_s,
    const float* __restrict__ WqT, const float* __restrict__ Wk,
    const float* __restrict__ g_in, const float* __restrict__ b_in,
    u16* __restrict__ Rg, float* __restrict__ c1ws, float* __restrict__ c2ws,
    float* __restrict__ yws, float* __restrict__ Zws, float* __restrict__ Aws)
{
    __shared__ float snb[128], qb[128], xch[128], red4[4];
    int bs = blockIdx.x, t = threadIdx.x;
    int b = bs / 7, s = bs - b * 7;
    int h = t & 127, half = t >> 7;
    float nv = 0.f;
    if (!half) {
        nv = mu[h] + expf(ls[h]) * slots_init[bs * 132 + h];
        slots[bs * 128 + h] = nv;
    }
    prep_tail(b, s, h, half, t, nv, g_s, b_s, WqT, Wk, g_in, b_in,
              Rg, c1ws, c2ws, yws, Zws, Aws, snb, qb, xch, red4);
}

// ---------------- kernel 2: streaming attention (64-row tile, 8 blk/CU) ----
// tile: 64 rows x 64 u32 bf16-pairs, XOR-swizzled (uint4 col q ^= row&15).
// LDS ~19.1 KB -> 8 blocks/CU = 32 waves/CU (hw max): latency-hiding x2,
// per-block critical path halved. Grid 64x64.
// pack: thread = (row r=t>>2, quarter p=t&3): 8 contiguous float4, row stats
//       via 4-lane shfl -> stats[128] LDS.
// phase1: MFMA 16x16x32_bf16, one acc per wave (16 rows). Softmax in C-frag
//       layout (s = lane&15, shfl over 16-group).
// phase2: (nh=t>>7, dp=t&63, sA=(t>>6)&1), 16 iters, n-paired pkfma.
__global__ __launch_bounds__(256, 8) void k_attn(
    const float* __restrict__ xin,
    const u16* __restrict__ Rg, const float* __restrict__ c1ws,
    const float* __restrict__ c2ws,
    float* __restrict__ yws, float* __restrict__ Zws, float* __restrict__ Aws)
{
    __shared__ u32 tile[4096];          // 16 KB
    __shared__ __align__(16) float wt[448];   // w fp32 [s][n] (n local 0..63)
    __shared__ __align__(8)  float stats[128];// (mean, rs) per row
    __shared__ float c1l[16], c2l[16];
    __shared__ float redp[4][8], redw[4][8];
    int t = threadIdx.x;
    int b = blockIdx.y;
    int n0 = blockIdx.x * 64;
    int lane = t & 63, wv = t >> 6;
    int ls = lane & 15, lg = lane >> 4;

    if (t < 16) {
        c1l[t] = (t < 7) ? c1ws[b * 8 + t] : 0.f;
        c2l[t] = (t < 7) ? c2ws[b * 8 + t] : 0.f;
    }

    // B-fragments (R) straight from global into VGPRs, reused all tiles
    bf16x8 bfr[4];
    {
        const u16* Rrow = Rg + ((size_t)b * 16 + ls) * 128;
        #pragma unroll
        for (int kk = 0; kk < 4; kk++)
            bfr[kk] = as_bf16x8(*(const uint4*)&Rrow[kk * 32 + lg * 8]);
    }

    // ---- pack + row stats ----
    {
        int r = t >> 2, p = t & 3;
        const float4* xg = (const float4*)(xin + ((size_t)b * 4096 + n0 + r) * 128 + p * 32);
        v2f smp = (v2f){0.f, 0.f}, sqp = (v2f){0.f, 0.f};
        #pragma unroll
        for (int i = 0; i < 8; i++) {
            float4 v = xg[i];
            v2f lo = (v2f){v.x, v.y}, hi = (v2f){v.z, v.w};
            smp = pkadd(smp, pkadd(lo, hi));
            sqp = pkfma(lo, lo, sqp);
            sqp = pkfma(hi, hi, sqp);
            int q = p * 4 + (i >> 1), rem = (i & 1) * 2;
            *(uint2*)&tile[(r * 16 + (q ^ (r & 15))) * 4 + rem] =
                make_uint2(pack2bf(v.x, v.y), pack2bf(v.z, v.w));
        }
        float sm = smp.x + smp.y, sq = sqp.x + sqp.y;
        sm += __shfl_xor(sm, 1); sq += __shfl_xor(sq, 1);
        sm += __shfl_xor(sm, 2); sq += __shfl_xor(sq, 2);
        if (!p) {
            float mean = sm * (1.0f / 128.0f);
            float var  = sq * (1.0f / 128.0f) - mean * mean;
            *(float2*)&stats[2 * r] = make_float2(mean, rsqrtf(var + LN_EPS_));
        }
    }
    __syncthreads();

    // ---- phase1: MFMA logits (one 16-row fragment per wave) ----
    f32x4 acc0 = {0.f, 0.f, 0.f, 0.f};
    {
        int m0 = wv * 16 + ls;
        #pragma unroll
        for (int kk = 0; kk < 4; kk++) {
            int q = kk * 4 + lg;
            bf16x8 a0 = as_bf16x8(*(const uint4*)&tile[(m0 * 16 + (q ^ ls)) * 4]);
            acc0 = __builtin_amdgcn_mfma_f32_16x16x32_bf16(a0, bfr[kk], acc0, 0, 0, 0);
        }
    }
    // ---- softmax epilogue in C-frag layout ----
    {
        float zsum = 0.f, asum = 0.f;
        float c1v = c1l[ls], c2v = c2l[ls];
        bool sv = ls < 7;
        int nbase = wv * 16 + lg * 4;
        #pragma unroll
        for (int r4 = 0; r4 < 4; r4++) {
            int n = nbase + r4;
            float2 stf = *(const float2*)&stats[2 * n];
            float L = sv ? (stf.y * (acc0[r4] - stf.x * c1v) + c2v) : -3.4e38f;
            float mx = L;
            mx = fmaxf(mx, __shfl_xor(mx, 1));
            mx = fmaxf(mx, __shfl_xor(mx, 2));
            mx = fmaxf(mx, __shfl_xor(mx, 4));
            mx = fmaxf(mx, __shfl_xor(mx, 8));
            float e = __expf(L - mx);
            float ssum = e;
            ssum += __shfl_xor(ssum, 1);
            ssum += __shfl_xor(ssum, 2);
            ssum += __shfl_xor(ssum, 4);
            ssum += __shfl_xor(ssum, 8);
            float p = e * (1.0f / ssum) + EPS_;
            float w = p * stf.y;
            if (sv) {
                wt[ls * 64 + n] = w;
                zsum += p;
                asum += w * stf.x;
            }
        }
        zsum += __shfl_xor(zsum, 16); zsum += __shfl_xor(zsum, 32);
        asum += __shfl_xor(asum, 16); asum += __shfl_xor(asum, 32);
        if (lane < 7) { redp[wv][lane] = zsum; redw[wv][lane] = asum; }
    }
    __syncthreads();
    if (t < 7)
        atomicAdd(&Zws[b * 8 + t],
                  redp[0][t] + redp[1][t] + redp[2][t] + redp[3][t]);
    else if (t >= 64 && t < 71) {
        int s = t - 64;
        atomicAdd(&Aws[b * 8 + s],
                  redw[0][s] + redw[1][s] + redw[2][s] + redw[3][s]);
    }

    // ---- phase2 ----
    int nh = t >> 7, dp = t & 63, sA = (t >> 6) & 1;
    v2f aclo[4], achi[4];
    #pragma unroll
    for (int k = 0; k < 4; k++) { aclo[k] = (v2f){0.f,0.f}; achi[k] = (v2f){0.f,0.f}; }
    int nbeg = nh * 32;
    #pragma unroll 4
    for (int n = nbeg; n < nbeg + 32; n += 2) {
        u32 x0 = tile[(n * 16 + ((dp >> 2) ^ (n & 15))) * 4 + (dp & 3)];
        u32 x1 = tile[((n + 1) * 16 + ((dp >> 2) ^ ((n + 1) & 15))) * 4 + (dp & 3)];
        v2f alo = (v2f){bflo(x0), bflo(x1)};
        v2f ahi = (v2f){bfhi(x0), bfhi(x1)};
        #pragma unroll
        for (int k = 0; k < 4; k++) {
            int s = sA + 2 * k;
            if (s < 7) {
                v2f wp = *(const v2f*)&wt[s * 64 + n];   // ds_read_b64, broadcast
                aclo[k] = pkfma(alo, wp, aclo[k]);
                achi[k] = pkfma(ahi, wp, achi[k]);
            }
        }
    }
    float* yb = yws + (size_t)b * 7 * 128;
    #pragma unroll
    for (int k = 0; k < 4; k++) {
        int s = sA + 2 * k;
        if (s < 7) {
            atomicAdd(&yb[s * 128 + 2 * dp],     aclo[k].x + aclo[k].y);
            atomicAdd(&yb[s * 128 + 2 * dp + 1], achi[k].x + achi[k].y);
        }
    }
}

// ---------------- kernel 3: slot update (GRU + MLP) + fused next-prep ------
__global__ __launch_bounds__(256) void k_update(
    float* __restrict__ slots, const float* __restrict__ yws,
    float* __restrict__ Zws, float* __restrict__ Aws,
    const float* __restrict__ g_in, const float* __restrict__ b_in,
    const u32* __restrict__ Pv, const u32* __restrict__ Pih,
    const u32* __restrict__ Phh, const float* __restrict__ b_ih,
    const float* __restrict__ b_hh, const float* __restrict__ g_m,
    const float* __restrict__ b_m, const u32* __restrict__ Pw1,
    const float* __restrict__ bb1, const u32* __restrict__ Pw2,
    const float* __restrict__ bb2, float* __restrict__ out,
    const float* __restrict__ g_s, const float* __restrict__ b_s,
    const float* __restrict__ WqT, const float* __restrict__ Wk,
    u16* __restrict__ Rg, float* __restrict__ c1ws, float* __restrict__ c2ws,
    float* __restrict__ ywz, int do_prep)
{
    __shared__ float ybuf[128], ub[128], hb[128], lb[128], t1b[256];
    __shared__ float ghx[384];
    __shared__ float up[128], op[128];
    __shared__ float redA[2], redB[2];
    __shared__ float snb[128], qb[128], xch[128], red4[4];
    int bs = blockIdx.x, t = threadIdx.x;
    int b = bs / 7, s = bs - b * 7;
    int h = t & 127, half = t >> 7;
    if (!half) {
        float Z = Zws[b * 8 + s], A = Aws[b * 8 + s];
        ybuf[h] = g_in[h] * (yws[bs * 128 + h] - A) / Z + b_in[h];
        hb[h] = slots[bs * 128 + h];
    }
    __syncthreads();
    // ---- u = Wv @ y : split-K ----
    {
        float a0 = 0.f, a1 = 0.f;
        int dp0 = half * 32;
        #pragma unroll 4
        for (int dp = dp0; dp < dp0 + 32; dp += 2) {
            u32 w0 = Pv[dp * 128 + h];
            u32 w1v = Pv[(dp + 1) * 128 + h];
            a0 += bflo(w0) * ybuf[2 * dp] + bfhi(w0) * ybuf[2 * dp + 1];
            a1 += bflo(w1v) * ybuf[2 * dp + 2] + bfhi(w1v) * ybuf[2 * dp + 3];
        }
        if (half) up[h] = a0 + a1;
        __syncthreads();
        if (!half) ub[h] = (a0 + a1) + up[h];
        __syncthreads();
    }
    // ---- GRU gates: lo -> gi(ub), hi -> gh(hb) ----
    float gv0, gv1, gv2;
    {
        const u32* P = half ? Phh : Pih;
        const float* src = half ? hb : ub;
        gv0 = half ? b_hh[h] : b_ih[h];
        gv1 = half ? b_hh[128 + h] : b_ih[128 + h];
        gv2 = half ? b_hh[256 + h] : b_ih[256 + h];
        #pragma unroll 4
        for (int dp = 0; dp < 64; dp++) {
            float x0 = src[2 * dp], x1 = src[2 * dp + 1];
            u32 w0 = P[dp * 384 + h];
            u32 w1v = P[dp * 384 + 128 + h];
            u32 w2v = P[dp * 384 + 256 + h];
            gv0 += bflo(w0) * x0 + bfhi(w0) * x1;
            gv1 += bflo(w1v) * x0 + bfhi(w1v) * x1;
            gv2 += bflo(w2v) * x0 + bfhi(w2v) * x1;
        }
        if (half) { ghx[h] = gv0; ghx[128 + h] = gv1; ghx[256 + h] = gv2; }
    }
    __syncthreads();
    float hv = 0.f;
    if (!half) {
        float rg = 1.0f / (1.0f + __expf(-(gv0 + ghx[h])));
        float zg = 1.0f / (1.0f + __expf(-(gv1 + ghx[128 + h])));
        float ng = tanhf(gv2 + rg * ghx[256 + h]);
        hv = (1.0f - zg) * ng + zg * hb[h];
        float sm2 = hv, sq2 = hv * hv;
        for (int m = 32; m >= 1; m >>= 1) { sm2 += __shfl_xor(sm2, m); sq2 += __shfl_xor(sq2, m); }
        if ((t & 63) == 0) { redA[t >> 6] = sm2; redB[t >> 6] = sq2; }
    }
    __syncthreads();
    if (!half) {
        float sm2 = redA[0] + redA[1], sq2 = redB[0] + redB[1];
        float mean = sm2 * (1.0f / 128.0f);
        float var  = sq2 * (1.0f / 128.0f) - mean * mean;
        float rsq = rsqrtf(var + LN_EPS_);
        lb[h] = (hv - mean) * rsq * g_m[h] + b_m[h];
    }
    __syncthreads();
    // ---- mlp1: 256 outs, one per thread ----
    {
        float m1 = bb1[t];
        #pragma unroll 4
        for (int dp = 0; dp < 64; dp++) {
            u32 w0 = Pw1[dp * 256 + t];
            m1 += bflo(w0) * lb[2 * dp] + bfhi(w0) * lb[2 * dp + 1];
        }
        t1b[t] = fmaxf(m1, 0.0f);
    }
    __syncthreads();
    // ---- mlp2: 128 outs, split-K ----
    float nv = 0.f;
    {
        float o0 = 0.f, o1 = 0.f;
        int mp0 = half * 64;
        #pragma unroll 4
        for (int mp = mp0; mp < mp0 + 64; mp += 2) {
            u32 w0 = Pw2[mp * 128 + h];
            u32 w1v = Pw2[(mp + 1) * 128 + h];
            o0 += bflo(w0) * t1b[2 * mp] + bfhi(w0) * t1b[2 * mp + 1];
            o1 += bflo(w1v) * t1b[2 * mp + 2] + bfhi(w1v) * t1b[2 * mp + 3];
        }
        if (half) op[h] = o0 + o1;
        __syncthreads();
        if (!half) {
            nv = hv + bb2[h] + (o0 + o1) + op[h];
            slots[bs * 128 + h] = nv;
            out[bs * 128 + h] = nv;
        }
    }
    if (do_prep) {
        __syncthreads();
        prep_tail(b, s, h, half, t, nv, g_s, b_s, WqT, Wk, g_in, b_in,
                  Rg, c1ws, c2ws, ywz, Zws, Aws, snb, qb, xch, red4);
    }
}

extern "C" void kernel_launch(void* const* d_in, const int* in_sizes, int n_in,
                              void* d_out, int out_size, void* d_ws, size_t ws_size,
                              hipStream_t stream) {
    const float* inputs     = (const float*)d_in[0];
    const float* slots_init = (const float*)d_in[1];
    const float* ln_in_g    = (const float*)d_in[2];
    const float* ln_in_b    = (const float*)d_in[3];
    const float* ln_s_g     = (const float*)d_in[4];
    const float* ln_s_b     = (const float*)d_in[5];
    const float* ln_m_g     = (const float*)d_in[6];
    const float* ln_m_b     = (const float*)d_in[7];
    const float* Wq         = (const float*)d_in[8];
    const float* Wk         = (const float*)d_in[9];
    const float* Wv         = (const float*)d_in[10];
    const float* W_ih       = (const float*)d_in[11];
    const float* W_hh       = (const float*)d_in[12];
    const float* b_ih       = (const float*)d_in[13];
    const float* b_hh       = (const float*)d_in[14];
    const float* mlp_w1     = (const float*)d_in[15];
    const float* mlp_b1     = (const float*)d_in[16];
    const float* mlp_w2     = (const float*)d_in[17];
    const float* mlp_b2     = (const float*)d_in[18];
    const float* slots_mu   = (const float*)d_in[19];
    const float* slots_ls   = (const float*)d_in[20];

    char* ws = (char*)d_ws;
    float* slots = (float*)(ws);                  // 229376
    u16*   Rg    = (u16*)  (ws + 229376);         // 262144 (bf16 R, 16 rows/b)
    float* c1ws  = (float*)(ws + 491520);         // 2048
    float* c2ws  = (float*)(ws + 493568);         // 2048
    float* yws   = (float*)(ws + 495616);         // 229376
    float* Zws   = (float*)(ws + 724992);         // 2048
    float* Aws   = (float*)(ws + 727040);         // 2048
    float* WqT   = (float*)(ws + 729088);         // 65536
    u32*   Pv    = (u32*)  (ws + 794624);         // 32768
    u32*   Pih   = (u32*)  (ws + 827392);         // 98304
    u32*   Phh   = (u32*)  (ws + 925696);         // 98304
    u32*   Pw1   = (u32*)  (ws + 1024000);        // 65536
    u32*   Pw2   = (u32*)  (ws + 1089536);        // 65536  -> total 1155072 B

    k_pack<<<560, 256, 0, stream>>>(Wq, Wv, W_ih, W_hh, mlp_w1, mlp_w2,
                                    WqT, Pv, Pih, Phh, Pw1, Pw2, (u32*)Rg);
    k_init_prep<<<448, 256, 0, stream>>>(slots_init, slots_mu, slots_ls, slots,
                                         ln_s_g, ln_s_b, WqT, Wk, ln_in_g, ln_in_b,
                                         Rg, c1ws, c2ws, yws, Zws, Aws);
    for (int it = 0; it < 3; it++) {
        k_attn<<<dim3(64, 64), 256, 0, stream>>>(inputs, Rg, c1ws, c2ws, yws, Zws, Aws);
        k_update<<<448, 256, 0, stream>>>(slots, yws, Zws, Aws, ln_in_g, ln_in_b,
                                          Pv, Pih, Phh, b_ih, b_hh,
                                          ln_m_g, ln_m_b, Pw1, mlp_b1, Pw2, mlp_b2,
                                          (float*)d_out,
                                          ln_s_g, ln_s_b, WqT, Wk,
                                          Rg, c1ws, c2ws, yws, (it < 2) ? 1 : 0);
    }
}

// Round 5
// 388.359 us; speedup vs baseline: 1.2006x; 1.2006x over previous
//
#include <hip/hip_runtime.h>
#include <hip/hip_bf16.h>
#include <stdint.h>

typedef unsigned int u32;
typedef unsigned short u16;
typedef float v2f __attribute__((ext_vector_type(2)));
typedef short bf16x8 __attribute__((ext_vector_type(8)));
typedef float f32x4 __attribute__((ext_vector_type(4)));

#define LN_EPS_ 1e-5f
#define EPS_ 1e-8f

__device__ __forceinline__ float bflo(u32 v){ return __uint_as_float(v << 16); }
__device__ __forceinline__ float bfhi(u32 v){ return __uint_as_float(v & 0xFFFF0000u); }
__device__ __forceinline__ u32 f2bf(float f){
    u32 x = __float_as_uint(f);
    return (x + 0x7FFFu + ((x >> 16) & 1u)) >> 16;
}
__device__ __forceinline__ u32 pack2bf(float a, float b){
    union { __hip_bfloat162 h; u32 u; } cv;
    cv.h = __float22bfloat162_rn(float2{a, b});
    return cv.u;
}
// packed fp32 math (gfx90a+/gfx950): 2 MACs per instruction
__device__ __forceinline__ v2f pkfma(v2f a, v2f b, v2f c){
    v2f d; asm("v_pk_fma_f32 %0, %1, %2, %3" : "=v"(d) : "v"(a), "v"(b), "v"(c)); return d;
}
__device__ __forceinline__ v2f pkadd(v2f a, v2f b){
    v2f d; asm("v_pk_add_f32 %0, %1, %2" : "=v"(d) : "v"(a), "v"(b)); return d;
}
__device__ __forceinline__ bf16x8 as_bf16x8(uint4 u){
    union { uint4 a; bf16x8 b; } c; c.a = u; return c.b;
}

// ---------------- kernel P: one-time weight prep ---------------------------
__global__ __launch_bounds__(256) void k_pack(
    const float* __restrict__ Wq, const float* __restrict__ Wv,
    const float* __restrict__ Wih, const float* __restrict__ Whh,
    const float* __restrict__ w1, const float* __restrict__ w2,
    float* __restrict__ WqT, u32* __restrict__ Pv, u32* __restrict__ Pih,
    u32* __restrict__ Phh, u32* __restrict__ Pw1, u32* __restrict__ Pw2,
    u32* __restrict__ Rg32)
{
    int i = blockIdx.x * 256 + threadIdx.x;
    if (i < 8192) {                                   // Pv
        int dp = i >> 7, o = i & 127;
        Pv[i] = pack2bf(Wv[o * 128 + 2 * dp], Wv[o * 128 + 2 * dp + 1]);
    } else if (i < 32768) {                           // Pih
        int r = i - 8192; int dp = r / 384, j = r - dp * 384;
        Pih[r] = pack2bf(Wih[j * 128 + 2 * dp], Wih[j * 128 + 2 * dp + 1]);
    } else if (i < 57344) {                           // Phh
        int r = i - 32768; int dp = r / 384, j = r - dp * 384;
        Phh[r] = pack2bf(Whh[j * 128 + 2 * dp], Whh[j * 128 + 2 * dp + 1]);
    } else if (i < 73728) {                           // Pw1
        int r = i - 57344; int dp = r >> 8, j = r & 255;
        Pw1[r] = pack2bf(w1[j * 128 + 2 * dp], w1[j * 128 + 2 * dp + 1]);
    } else if (i < 90112) {                           // Pw2
        int r = i - 73728; int mp = r >> 7, o = r & 127;
        Pw2[r] = pack2bf(w2[o * 256 + 2 * mp], w2[o * 256 + 2 * mp + 1]);
    } else if (i < 106496) {                          // WqT fp32
        int r = i - 90112; int d = r >> 7, o = r & 127;
        WqT[r] = Wq[o * 128 + d];
    } else if (i < 143360) {                          // zero Rg rows 7..15
        int r = i - 106496; int b = r / 576, rem = r - b * 576;
        Rg32[b * 1024 + 448 + rem] = 0;
    }
}

// ---------------- prep tail: LN(slot) -> q -> r -> Rg/c1/c2 ---------------
// 256 threads; lo half (t<128) holds nv = new slot value for h = t&127.
__device__ __forceinline__ void prep_tail(
    int b, int s, int h, int half, int t, float nv,
    const float* __restrict__ g_s, const float* __restrict__ b_s,
    const float* __restrict__ WqT, const float* __restrict__ Wk,
    const float* __restrict__ g_in, const float* __restrict__ b_in,
    u16* __restrict__ Rg, float* __restrict__ c1ws, float* __restrict__ c2ws,
    float* snb, float* qb, float* xch, float* red4)
{
    if (!half) {
        float smv = nv, sqv = nv * nv;
        for (int m = 32; m >= 1; m >>= 1) { smv += __shfl_xor(smv, m); sqv += __shfl_xor(sqv, m); }
        if ((t & 63) == 0) { red4[(t >> 6) * 2] = smv; red4[(t >> 6) * 2 + 1] = sqv; }
    }
    __syncthreads();
    float mean = (red4[0] + red4[2]) * (1.0f / 128.0f);
    float var  = (red4[1] + red4[3]) * (1.0f / 128.0f) - mean * mean;
    float rsv = rsqrtf(var + LN_EPS_);
    if (!half) snb[h] = (nv - mean) * rsv * g_s[h] + b_s[h];
    __syncthreads();
    // q[h] = sum_d WqT[d][h] * snb[d], split-K over halves
    {
        float q0 = 0.f, q1 = 0.f;
        int d0 = half * 64;
        #pragma unroll 4
        for (int d = d0; d < d0 + 64; d += 2) {
            q0 += WqT[d * 128 + h] * snb[d];
            q1 += WqT[(d + 1) * 128 + h] * snb[d + 1];
        }
        if (half) xch[h] = q0 + q1;
        __syncthreads();
        if (!half) qb[h] = q0 + q1 + xch[h];
        __syncthreads();
    }
    // r[h] = sum_j Wk[j][h] * qb[j], split-K over halves
    float r0 = 0.f, r1 = 0.f;
    int j0 = half * 64;
    #pragma unroll 4
    for (int j = j0; j < j0 + 64; j += 2) {
        r0 += Wk[j * 128 + h] * qb[j];
        r1 += Wk[(j + 1) * 128 + h] * qb[j + 1];
    }
    if (half) xch[h] = r0 + r1;
    __syncthreads();
    if (!half) {
        float r = (r0 + r1 + xch[h]) * 0.08838834764831845f;   // 128^-0.5
        float rt  = g_in[h] * r;
        float c2v = b_in[h] * r;
        Rg[((size_t)b * 16 + s) * 128 + h] = (u16)f2bf(rt);
        float c1p = rt, c2p = c2v;
        for (int m = 32; m >= 1; m >>= 1) { c1p += __shfl_xor(c1p, m); c2p += __shfl_xor(c2p, m); }
        if ((t & 63) == 0) { red4[(t >> 6) * 2] = c1p; red4[(t >> 6) * 2 + 1] = c2p; }
    }
    __syncthreads();
    if (t == 0) {
        c1ws[b * 8 + s] = red4[0] + red4[2];
        c2ws[b * 8 + s] = red4[1] + red4[3];
    }
}

// ---------------- kernel 0: slots init + prep for iter 0 -------------------
__global__ __launch_bounds__(256) void k_init_prep(
    const float* __restrict__ slots_init, const float* __restrict__ mu,
    const float* __restrict__ ls, float* __restrict__ slots,
    const float* __restrict__ g_s, const float* __restrict__ b_s,
    const float* __restrict__ WqT, const float* __restrict__ Wk,
    const float* __restrict__ g_in, const float* __restrict__ b_in,
    u16* __restrict__ Rg, float* __restrict__ c1ws, float* __restrict__ c2ws)
{
    __shared__ float snb[128], qb[128], xch[128], red4[4];
    int bs = blockIdx.x, t = threadIdx.x;
    int b = bs / 7, s = bs - b * 7;
    int h = t & 127, half = t >> 7;
    float nv = 0.f;
    if (!half) {
        nv = mu[h] + expf(ls[h]) * slots_init[bs * 132 + h];
        slots[bs * 128 + h] = nv;
    }
    prep_tail(b, s, h, half, t, nv, g_s, b_s, WqT, Wk, g_in, b_in,
              Rg, c1ws, c2ws, snb, qb, xch, red4);
}

// ---------------- kernel 2: streaming attention (64-row tile, 8 blk/CU) ----
// NO GLOBAL ATOMICS: per-block partials streamed to ypart/Zp/Ap with plain
// coalesced stores; k_update reduces them. (r0-r4 evidence: WRITE_SIZE
// tracked atomic count exactly; memory-side atomic RMW was the invariant
// ~80 us wall.)
// tile: 64 rows x 64 u32 bf16-pairs, XOR-swizzled (uint4 col q ^= row&15).
// phase1: MFMA 16x16x32_bf16, softmax in C-frag layout.
// phase2: (nh=t>>7, dp=t&63, sA=(t>>6)&1), n-paired pkfma -> float2 stores.
__global__ __launch_bounds__(256, 8) void k_attn(
    const float* __restrict__ xin,
    const u16* __restrict__ Rg, const float* __restrict__ c1ws,
    const float* __restrict__ c2ws,
    float* __restrict__ ypart, float* __restrict__ Zp, float* __restrict__ Ap)
{
    __shared__ u32 tile[4096];          // 16 KB
    __shared__ __align__(16) float wt[448];   // w fp32 [s][n] (n local 0..63)
    __shared__ __align__(8)  float stats[128];// (mean, rs) per row
    __shared__ float c1l[16], c2l[16];
    __shared__ float redp[4][8], redw[4][8];
    int t = threadIdx.x;
    int b = blockIdx.y;
    int n0 = blockIdx.x * 64;
    int lane = t & 63, wv = t >> 6;
    int ls = lane & 15, lg = lane >> 4;

    if (t < 16) {
        c1l[t] = (t < 7) ? c1ws[b * 8 + t] : 0.f;
        c2l[t] = (t < 7) ? c2ws[b * 8 + t] : 0.f;
    }

    // B-fragments (R) straight from global into VGPRs, reused all tiles
    bf16x8 bfr[4];
    {
        const u16* Rrow = Rg + ((size_t)b * 16 + ls) * 128;
        #pragma unroll
        for (int kk = 0; kk < 4; kk++)
            bfr[kk] = as_bf16x8(*(const uint4*)&Rrow[kk * 32 + lg * 8]);
    }

    // ---- pack + row stats ----
    {
        int r = t >> 2, p = t & 3;
        const float4* xg = (const float4*)(xin + ((size_t)b * 4096 + n0 + r) * 128 + p * 32);
        v2f smp = (v2f){0.f, 0.f}, sqp = (v2f){0.f, 0.f};
        #pragma unroll
        for (int i = 0; i < 8; i++) {
            float4 v = xg[i];
            v2f lo = (v2f){v.x, v.y}, hi = (v2f){v.z, v.w};
            smp = pkadd(smp, pkadd(lo, hi));
            sqp = pkfma(lo, lo, sqp);
            sqp = pkfma(hi, hi, sqp);
            int q = p * 4 + (i >> 1), rem = (i & 1) * 2;
            *(uint2*)&tile[(r * 16 + (q ^ (r & 15))) * 4 + rem] =
                make_uint2(pack2bf(v.x, v.y), pack2bf(v.z, v.w));
        }
        float sm = smp.x + smp.y, sq = sqp.x + sqp.y;
        sm += __shfl_xor(sm, 1); sq += __shfl_xor(sq, 1);
        sm += __shfl_xor(sm, 2); sq += __shfl_xor(sq, 2);
        if (!p) {
            float mean = sm * (1.0f / 128.0f);
            float var  = sq * (1.0f / 128.0f) - mean * mean;
            *(float2*)&stats[2 * r] = make_float2(mean, rsqrtf(var + LN_EPS_));
        }
    }
    __syncthreads();

    // ---- phase1: MFMA logits (one 16-row fragment per wave) ----
    f32x4 acc0 = {0.f, 0.f, 0.f, 0.f};
    {
        int m0 = wv * 16 + ls;
        #pragma unroll
        for (int kk = 0; kk < 4; kk++) {
            int q = kk * 4 + lg;
            bf16x8 a0 = as_bf16x8(*(const uint4*)&tile[(m0 * 16 + (q ^ ls)) * 4]);
            acc0 = __builtin_amdgcn_mfma_f32_16x16x32_bf16(a0, bfr[kk], acc0, 0, 0, 0);
        }
    }
    // ---- softmax epilogue in C-frag layout ----
    {
        float zsum = 0.f, asum = 0.f;
        float c1v = c1l[ls], c2v = c2l[ls];
        bool sv = ls < 7;
        int nbase = wv * 16 + lg * 4;
        #pragma unroll
        for (int r4 = 0; r4 < 4; r4++) {
            int n = nbase + r4;
            float2 stf = *(const float2*)&stats[2 * n];
            float L = sv ? (stf.y * (acc0[r4] - stf.x * c1v) + c2v) : -3.4e38f;
            float mx = L;
            mx = fmaxf(mx, __shfl_xor(mx, 1));
            mx = fmaxf(mx, __shfl_xor(mx, 2));
            mx = fmaxf(mx, __shfl_xor(mx, 4));
            mx = fmaxf(mx, __shfl_xor(mx, 8));
            float e = __expf(L - mx);
            float ssum = e;
            ssum += __shfl_xor(ssum, 1);
            ssum += __shfl_xor(ssum, 2);
            ssum += __shfl_xor(ssum, 4);
            ssum += __shfl_xor(ssum, 8);
            float p = e * (1.0f / ssum) + EPS_;
            float w = p * stf.y;
            if (sv) {
                wt[ls * 64 + n] = w;
                zsum += p;
                asum += w * stf.x;
            }
        }
        zsum += __shfl_xor(zsum, 16); zsum += __shfl_xor(zsum, 32);
        asum += __shfl_xor(asum, 16); asum += __shfl_xor(asum, 32);
        if (lane < 7) { redp[wv][lane] = zsum; redw[wv][lane] = asum; }
    }
    __syncthreads();
    if (t < 7)
        Zp[((size_t)b * 64 + blockIdx.x) * 8 + t] =
            redp[0][t] + redp[1][t] + redp[2][t] + redp[3][t];
    else if (t >= 64 && t < 71) {
        int s = t - 64;
        Ap[((size_t)b * 64 + blockIdx.x) * 8 + s] =
            redw[0][s] + redw[1][s] + redw[2][s] + redw[3][s];
    }

    // ---- phase2 ----
    int nh = t >> 7, dp = t & 63, sA = (t >> 6) & 1;
    v2f aclo[4], achi[4];
    #pragma unroll
    for (int k = 0; k < 4; k++) { aclo[k] = (v2f){0.f,0.f}; achi[k] = (v2f){0.f,0.f}; }
    int nbeg = nh * 32;
    #pragma unroll 4
    for (int n = nbeg; n < nbeg + 32; n += 2) {
        u32 x0 = tile[(n * 16 + ((dp >> 2) ^ (n & 15))) * 4 + (dp & 3)];
        u32 x1 = tile[((n + 1) * 16 + ((dp >> 2) ^ ((n + 1) & 15))) * 4 + (dp & 3)];
        v2f alo = (v2f){bflo(x0), bflo(x1)};
        v2f ahi = (v2f){bfhi(x0), bfhi(x1)};
        #pragma unroll
        for (int k = 0; k < 4; k++) {
            int s = sA + 2 * k;
            if (s < 7) {
                v2f wp = *(const v2f*)&wt[s * 64 + n];   // ds_read_b64, broadcast
                aclo[k] = pkfma(alo, wp, aclo[k]);
                achi[k] = pkfma(ahi, wp, achi[k]);
            }
        }
    }
    // plain coalesced partial stores (replaces 7.3M global atomics)
    float* yp = ypart + (((size_t)b * 64 + blockIdx.x) * 2 + nh) * 896;
    #pragma unroll
    for (int k = 0; k < 4; k++) {
        int s = sA + 2 * k;
        if (s < 7) {
            *(float2*)&yp[s * 128 + 2 * dp] =
                make_float2(aclo[k].x + aclo[k].y, achi[k].x + achi[k].y);
        }
    }
}

// ---------------- kernel 3: partial-reduce + slot update (GRU+MLP) + prep --
__global__ __launch_bounds__(256) void k_update(
    float* __restrict__ slots, const float* __restrict__ ypart,
    const float* __restrict__ Zp, const float* __restrict__ Ap,
    const float* __restrict__ g_in, const float* __restrict__ b_in,
    const u32* __restrict__ Pv, const u32* __restrict__ Pih,
    const u32* __restrict__ Phh, const float* __restrict__ b_ih,
    const float* __restrict__ b_hh, const float* __restrict__ g_m,
    const float* __restrict__ b_m, const u32* __restrict__ Pw1,
    const float* __restrict__ bb1, const u32* __restrict__ Pw2,
    const float* __restrict__ bb2, float* __restrict__ out,
    const float* __restrict__ g_s, const float* __restrict__ b_s,
    const float* __restrict__ WqT, const float* __restrict__ Wk,
    u16* __restrict__ Rg, float* __restrict__ c1ws, float* __restrict__ c2ws,
    int do_prep)
{
    __shared__ float ybuf[128], ub[128], hb[128], lb[128], t1b[256];
    __shared__ float ghx[384];
    __shared__ float up[128], op[128];
    __shared__ float redA[2], redB[2];
    __shared__ float snb[128], qb[128], xch[128], red4[4];
    __shared__ float Zsh, Ash;
    int bs = blockIdx.x, t = threadIdx.x;
    int b = bs / 7, s = bs - b * 7;
    int h = t & 127, half = t >> 7;
    // ---- reduce y partials: each thread sums 64 (tile,nh) combos ----
    float ysum = 0.f;
    {
        const float* bp = ypart + ((size_t)(b * 128 + half * 64)) * 896 + s * 128 + h;
        #pragma unroll 8
        for (int c = 0; c < 64; c++) ysum += bp[(size_t)c * 896];
    }
    // ---- reduce Z/A partials on waves 0 and 1 ----
    if (t < 64) {
        float z = Zp[((size_t)b * 64 + t) * 8 + s];
        for (int m = 32; m >= 1; m >>= 1) z += __shfl_xor(z, m);
        if (t == 0) Zsh = z;
    } else if (t < 128) {
        float a_ = Ap[((size_t)b * 64 + (t - 64)) * 8 + s];
        for (int m = 32; m >= 1; m >>= 1) a_ += __shfl_xor(a_, m);
        if (t == 64) Ash = a_;
    }
    if (half) up[h] = ysum;
    __syncthreads();
    if (!half) {
        float ytot = ysum + up[h];
        ybuf[h] = g_in[h] * (ytot - Ash) / Zsh + b_in[h];
        hb[h] = slots[bs * 128 + h];
    }
    __syncthreads();
    // ---- u = Wv @ y : split-K ----
    {
        float a0 = 0.f, a1 = 0.f;
        int dp0 = half * 32;
        #pragma unroll 4
        for (int dp = dp0; dp < dp0 + 32; dp += 2) {
            u32 w0 = Pv[dp * 128 + h];
            u32 w1v = Pv[(dp + 1) * 128 + h];
            a0 += bflo(w0) * ybuf[2 * dp] + bfhi(w0) * ybuf[2 * dp + 1];
            a1 += bflo(w1v) * ybuf[2 * dp + 2] + bfhi(w1v) * ybuf[2 * dp + 3];
        }
        if (half) up[h] = a0 + a1;
        __syncthreads();
        if (!half) ub[h] = (a0 + a1) + up[h];
        __syncthreads();
    }
    // ---- GRU gates: lo -> gi(ub), hi -> gh(hb) ----
    float gv0, gv1, gv2;
    {
        const u32* P = half ? Phh : Pih;
        const float* src = half ? hb : ub;
        gv0 = half ? b_hh[h] : b_ih[h];
        gv1 = half ? b_hh[128 + h] : b_ih[128 + h];
        gv2 = half ? b_hh[256 + h] : b_ih[256 + h];
        #pragma unroll 4
        for (int dp = 0; dp < 64; dp++) {
            float x0 = src[2 * dp], x1 = src[2 * dp + 1];
            u32 w0 = P[dp * 384 + h];
            u32 w1v = P[dp * 384 + 128 + h];
            u32 w2v = P[dp * 384 + 256 + h];
            gv0 += bflo(w0) * x0 + bfhi(w0) * x1;
            gv1 += bflo(w1v) * x0 + bfhi(w1v) * x1;
            gv2 += bflo(w2v) * x0 + bfhi(w2v) * x1;
        }
        if (half) { ghx[h] = gv0; ghx[128 + h] = gv1; ghx[256 + h] = gv2; }
    }
    __syncthreads();
    float hv = 0.f;
    if (!half) {
        float rg = 1.0f / (1.0f + __expf(-(gv0 + ghx[h])));
        float zg = 1.0f / (1.0f + __expf(-(gv1 + ghx[128 + h])));
        float ng = tanhf(gv2 + rg * ghx[256 + h]);
        hv = (1.0f - zg) * ng + zg * hb[h];
        float sm2 = hv, sq2 = hv * hv;
        for (int m = 32; m >= 1; m >>= 1) { sm2 += __shfl_xor(sm2, m); sq2 += __shfl_xor(sq2, m); }
        if ((t & 63) == 0) { redA[t >> 6] = sm2; redB[t >> 6] = sq2; }
    }
    __syncthreads();
    if (!half) {
        float sm2 = redA[0] + redA[1], sq2 = redB[0] + redB[1];
        float mean = sm2 * (1.0f / 128.0f);
        float var  = sq2 * (1.0f / 128.0f) - mean * mean;
        float rsq = rsqrtf(var + LN_EPS_);
        lb[h] = (hv - mean) * rsq * g_m[h] + b_m[h];
    }
    __syncthreads();
    // ---- mlp1: 256 outs, one per thread ----
    {
        float m1 = bb1[t];
        #pragma unroll 4
        for (int dp = 0; dp < 64; dp++) {
            u32 w0 = Pw1[dp * 256 + t];
            m1 += bflo(w0) * lb[2 * dp] + bfhi(w0) * lb[2 * dp + 1];
        }
        t1b[t] = fmaxf(m1, 0.0f);
    }
    __syncthreads();
    // ---- mlp2: 128 outs, split-K ----
    float nv = 0.f;
    {
        float o0 = 0.f, o1 = 0.f;
        int mp0 = half * 64;
        #pragma unroll 4
        for (int mp = mp0; mp < mp0 + 64; mp += 2) {
            u32 w0 = Pw2[mp * 128 + h];
            u32 w1v = Pw2[(mp + 1) * 128 + h];
            o0 += bflo(w0) * t1b[2 * mp] + bfhi(w0) * t1b[2 * mp + 1];
            o1 += bflo(w1v) * t1b[2 * mp + 2] + bfhi(w1v) * t1b[2 * mp + 3];
        }
        if (half) op[h] = o0 + o1;
        __syncthreads();
        if (!half) {
            nv = hv + bb2[h] + (o0 + o1) + op[h];
            slots[bs * 128 + h] = nv;
            out[bs * 128 + h] = nv;
        }
    }
    if (do_prep) {
        __syncthreads();
        prep_tail(b, s, h, half, t, nv, g_s, b_s, WqT, Wk, g_in, b_in,
                  Rg, c1ws, c2ws, snb, qb, xch, red4);
    }
}

extern "C" void kernel_launch(void* const* d_in, const int* in_sizes, int n_in,
                              void* d_out, int out_size, void* d_ws, size_t ws_size,
                              hipStream_t stream) {
    const float* inputs     = (const float*)d_in[0];
    const float* slots_init = (const float*)d_in[1];
    const float* ln_in_g    = (const float*)d_in[2];
    const float* ln_in_b    = (const float*)d_in[3];
    const float* ln_s_g     = (const float*)d_in[4];
    const float* ln_s_b     = (const float*)d_in[5];
    const float* ln_m_g     = (const float*)d_in[6];
    const float* ln_m_b     = (const float*)d_in[7];
    const float* Wq         = (const float*)d_in[8];
    const float* Wk         = (const float*)d_in[9];
    const float* Wv         = (const float*)d_in[10];
    const float* W_ih       = (const float*)d_in[11];
    const float* W_hh       = (const float*)d_in[12];
    const float* b_ih       = (const float*)d_in[13];
    const float* b_hh       = (const float*)d_in[14];
    const float* mlp_w1     = (const float*)d_in[15];
    const float* mlp_b1     = (const float*)d_in[16];
    const float* mlp_w2     = (const float*)d_in[17];
    const float* mlp_b2     = (const float*)d_in[18];
    const float* slots_mu   = (const float*)d_in[19];
    const float* slots_ls   = (const float*)d_in[20];

    char* ws = (char*)d_ws;
    float* slots = (float*)(ws);                  // 229376
    u16*   Rg    = (u16*)  (ws + 229376);         // 262144 (bf16 R, 16 rows/b)
    float* c1ws  = (float*)(ws + 491520);         // 2048
    float* c2ws  = (float*)(ws + 493568);         // 2048
    float* WqT   = (float*)(ws + 495616);         // 65536
    u32*   Pv    = (u32*)  (ws + 561152);         // 32768
    u32*   Pih   = (u32*)  (ws + 593920);         // 98304
    u32*   Phh   = (u32*)  (ws + 692224);         // 98304
    u32*   Pw1   = (u32*)  (ws + 790528);         // 65536
    u32*   Pw2   = (u32*)  (ws + 856064);         // 65536
    float* Zp    = (float*)(ws + 921600);         // 131072
    float* Ap    = (float*)(ws + 1052672);        // 131072
    float* ypart = (float*)(ws + 1183744);        // 29360128 -> total ~30.5 MB

    k_pack<<<560, 256, 0, stream>>>(Wq, Wv, W_ih, W_hh, mlp_w1, mlp_w2,
                                    WqT, Pv, Pih, Phh, Pw1, Pw2, (u32*)Rg);
    k_init_prep<<<448, 256, 0, stream>>>(slots_init, slots_mu, slots_ls, slots,
                                         ln_s_g, ln_s_b, WqT, Wk, ln_in_g, ln_in_b,
                                         Rg, c1ws, c2ws);
    for (int it = 0; it < 3; it++) {
        k_attn<<<dim3(64, 64), 256, 0, stream>>>(inputs, Rg, c1ws, c2ws,
                                                 ypart, Zp, Ap);
        k_update<<<448, 256, 0, stream>>>(slots, ypart, Zp, Ap, ln_in_g, ln_in_b,
                                          Pv, Pih, Phh, b_ih, b_hh,
                                          ln_m_g, ln_m_b, Pw1, mlp_b1, Pw2, mlp_b2,
                                          (float*)d_out,
                                          ln_s_g, ln_s_b, WqT, Wk,
                                          Rg, c1ws, c2ws, (it < 2) ? 1 : 0);
    }
}